// Round 1
// 540.605 us; speedup vs baseline: 1.0276x; 1.0276x over previous
//
#include <hip/hip_runtime.h>

#define BB 16
#define NN 2048
#define DD 128

typedef __attribute__((ext_vector_type(8))) __bf16 bf16x8;
typedef __attribute__((ext_vector_type(4))) float f32x4;
typedef __attribute__((ext_vector_type(4))) unsigned int u32x4;
typedef __attribute__((address_space(3))) unsigned int lds_u32;
typedef __attribute__((address_space(1))) const unsigned int glob_u32;

static __device__ __forceinline__ unsigned short f2b(float f) {
  union { float f; unsigned int u; } c; c.f = f;
  unsigned int u = c.u;
  unsigned int r = (u + 0x7FFFu + ((u >> 16) & 1u)) >> 16;
  return (unsigned short)r;
}
static __device__ __forceinline__ float b2f(unsigned short u) {
  union { unsigned int u; float f; } c; c.u = ((unsigned int)u) << 16;
  return c.f;
}

// WT[l][e][d] = bf16(W[l][d][e])  -- 96 KB total, L2-resident afterwards
__global__ void k_wt(const float* __restrict__ W, unsigned short* __restrict__ WT) {
  __shared__ float t[64][65];
  int l = blockIdx.z, d0 = blockIdx.x * 64, e0 = blockIdx.y * 64;
  int tid = threadIdx.x;
  const float* src = W + (size_t)l * DD * DD;
  for (int p = 0; p < 16; ++p) {
    int idx = p * 256 + tid;
    int d = idx >> 6, e = idx & 63;
    t[e][d] = src[(size_t)(d0 + d) * DD + (e0 + e)];
  }
  __syncthreads();
  unsigned short* dst = WT + (size_t)l * DD * DD;
  for (int p = 0; p < 4; ++p) {
    int idx = p * 256 + tid;
    int e = idx >> 4, d4 = (idx & 15) * 4;
    ushort4 r;
    r.x = f2b(t[e][d4 + 0]); r.y = f2b(t[e][d4 + 1]);
    r.z = f2b(t[e][d4 + 2]); r.w = f2b(t[e][d4 + 3]);
    *(ushort4*)(dst + (size_t)(e0 + e) * DD + (d0 + d4)) = r;
  }
}

// Merged: x<1024 -> adj transpose tile; x>=1024 -> layer-0 gemm1 (X fp32, WT global frags)
__global__ __launch_bounds__(256) void k_pre(const float* __restrict__ adj,
                                             unsigned short* __restrict__ adjT,
                                             const float* __restrict__ X,
                                             const unsigned short* __restrict__ WT,
                                             unsigned short* __restrict__ hwT) {
  int b = blockIdx.y, x = blockIdx.x, tid = threadIdx.x;
  if (x < 1024) {
    __shared__ float t[64][65];
    int j0 = (x >> 5) * 64, i0 = (x & 31) * 64;
    const float* src = adj + (size_t)b * NN * NN;
    for (int p = 0; p < 16; ++p) {
      int idx = p * 256 + tid;
      int i = idx >> 6, j = idx & 63;
      t[j][i] = src[(size_t)(i0 + i) * NN + (j0 + j)];
    }
    __syncthreads();
    unsigned short* dst = adjT + (size_t)b * NN * NN;
    for (int p = 0; p < 4; ++p) {
      int idx = p * 256 + tid;
      int j = idx >> 4, i4 = (idx & 15) * 4;
      ushort4 r;
      r.x = f2b(t[j][i4 + 0]); r.y = f2b(t[j][i4 + 1]);
      r.z = f2b(t[j][i4 + 2]); r.w = f2b(t[j][i4 + 3]);
      *(ushort4*)(dst + (size_t)(j0 + j) * NN + (i0 + i4)) = r;
    }
  } else {
    int i0 = (x - 1024) * 64;
    int lane = tid & 63, w = tid >> 6;
    int q = lane >> 4, m = lane & 15;
    f32x4 acc[8];
#pragma unroll
    for (int t = 0; t < 8; ++t)
#pragma unroll
      for (int r = 0; r < 4; ++r) acc[t][r] = 0.f;
    int irow = i0 + w * 16 + m;
    const float* hrow = X + ((size_t)b * NN + irow) * DD;
#pragma unroll
    for (int kk = 0; kk < 4; ++kk) {
      int d0 = kk * 32 + q * 8;
      float4 h0 = *(const float4*)(hrow + d0);
      float4 h1 = *(const float4*)(hrow + d0 + 4);
      union { bf16x8 v; unsigned short s[8]; } ub;
      ub.s[0] = f2b(h0.x); ub.s[1] = f2b(h0.y); ub.s[2] = f2b(h0.z); ub.s[3] = f2b(h0.w);
      ub.s[4] = f2b(h1.x); ub.s[5] = f2b(h1.y); ub.s[6] = f2b(h1.z); ub.s[7] = f2b(h1.w);
#pragma unroll
      for (int mt = 0; mt < 8; ++mt) {
        bf16x8 af = *(const bf16x8*)(WT + (mt * 16 + m) * 128 + d0);
        acc[mt] = __builtin_amdgcn_mfma_f32_16x16x32_bf16(af, ub.v, acc[mt], 0, 0, 0);
      }
    }
    unsigned short* dst = hwT + (size_t)b * DD * NN;
#pragma unroll
    for (int mt = 0; mt < 8; ++mt)
#pragma unroll
      for (int r = 0; r < 4; ++r)
        dst[(size_t)(mt * 16 + q * 4 + r) * NN + irow] = f2b(acc[mt][r]);
  }
}

// Fused per-layer kernel: tile 64 j-rows x 128 e-cols, full K=NN.
//   agg[j][e] = sum_i adjT[j][i]*hwT[e][i]   (fp32 accum over full K -- no bf16 partials)
//   z = agg + bias + res; LN + ReLU -> outf; (doW) gemm1 z@Wn -> hwTn (transposed [e][i])
// Grid 32x16 = 512 blocks, 256 thr, LDS 68KB -> 2 blocks/CU (8 waves/CU, cross-block overlap).
__global__ __launch_bounds__(256) void k_layer(const unsigned short* __restrict__ adjT,
                                               const unsigned short* __restrict__ hwT,
                                               const float* __restrict__ res,
                                               const float* __restrict__ bias,
                                               const float* __restrict__ gamma,
                                               const float* __restrict__ beta,
                                               const unsigned short* __restrict__ WTn,
                                               float* __restrict__ outf,
                                               unsigned short* __restrict__ hwTn,
                                               int doW) {
  __shared__ float z[64 * 132];
  __shared__ float smu[64], srs[64];
  // union region: gemm staging (sA 64x64 + sH 128x64 bf16 = 24KB) then sW (128x132 bf16)
  __shared__ __align__(16) unsigned short sWS[128 * 132];
  unsigned short* sA = sWS;          // 4096 halves
  unsigned short* sH = sWS + 4096;   // 8192 halves
  unsigned short* sW = sWS;

  int tid = threadIdx.x;
  int lane = tid & 63, w = tid >> 6;
  int q = lane >> 4, m = lane & 15;
  int wj = w & 1, we = w >> 1;
  int b = blockIdx.y, j0 = blockIdx.x * 64;
  const unsigned short* At = adjT + (size_t)b * NN * NN;
  const unsigned short* Ht = hwT + (size_t)b * DD * NN;

  // Pre-swizzled global source, linear LDS dest (rule: both-sides-or-neither).
  // chunk p -> LDS chunk p; src row r=p>>3, col-group cg=(p&7)^(r&7).
  const unsigned short* aSrc[2];
  const unsigned short* hSrc[4];
#pragma unroll
  for (int it = 0; it < 2; ++it) {
    int p = (it * 4 + w) * 64 + lane;
    int r = p >> 3, cg = (p & 7) ^ (r & 7);
    aSrc[it] = At + (size_t)(j0 + r) * NN + cg * 8;
  }
#pragma unroll
  for (int it = 0; it < 4; ++it) {
    int p = (it * 4 + w) * 64 + lane;
    int r = p >> 3, cg = (p & 7) ^ (r & 7);
    hSrc[it] = Ht + (size_t)r * NN + cg * 8;
  }

  f32x4 acc[2][4];
#pragma unroll
  for (int i = 0; i < 2; ++i)
#pragma unroll
    for (int j = 0; j < 4; ++j)
#pragma unroll
      for (int r = 0; r < 4; ++r) acc[i][j][r] = 0.f;

  for (int k0 = 0; k0 < NN; k0 += 64) {
    __syncthreads();
#pragma unroll
    for (int it = 0; it < 2; ++it) {
      __builtin_amdgcn_global_load_lds((glob_u32*)aSrc[it],
                                       (lds_u32*)(sA + (it * 4 + w) * 512), 16, 0, 0);
      aSrc[it] += 64;
    }
#pragma unroll
    for (int it = 0; it < 4; ++it) {
      __builtin_amdgcn_global_load_lds((glob_u32*)hSrc[it],
                                       (lds_u32*)(sH + (it * 4 + w) * 512), 16, 0, 0);
      hSrc[it] += 64;
    }
    __syncthreads();
#pragma unroll
    for (int kk = 0; kk < 2; ++kk) {
      bf16x8 af[2], bf[4];
#pragma unroll
      for (int mt = 0; mt < 2; ++mt) {
        int r = wj * 32 + mt * 16 + m;
        int c = (kk * 4 + q) ^ (r & 7);
        af[mt] = *(const bf16x8*)(sA + r * 64 + c * 8);
      }
#pragma unroll
      for (int nt = 0; nt < 4; ++nt) {
        int r = we * 64 + nt * 16 + m;
        int c = (kk * 4 + q) ^ (r & 7);
        bf[nt] = *(const bf16x8*)(sH + r * 64 + c * 8);
      }
#pragma unroll
      for (int mt = 0; mt < 2; ++mt)
#pragma unroll
        for (int nt = 0; nt < 4; ++nt)
          acc[mt][nt] = __builtin_amdgcn_mfma_f32_16x16x32_bf16(af[mt], bf[nt], acc[mt][nt], 0, 0, 0);
    }
  }

  // E1: spill accumulators (full-K fp32 sums) into z
#pragma unroll
  for (int mt = 0; mt < 2; ++mt)
#pragma unroll
    for (int nt = 0; nt < 4; ++nt)
#pragma unroll
      for (int r = 0; r < 4; ++r) {
        int row = wj * 32 + mt * 16 + q * 4 + r;
        int col = we * 64 + nt * 16 + m;
        z[row * 132 + col] = acc[mt][nt][r];
      }
  __syncthreads();  // all staging reads done; sWS region now reusable as sW

  if (doW) {
#pragma unroll
    for (int p = 0; p < 8; ++p) {  // 128x128 ushorts, 16B chunks from WTn[e][d]
      int idx = p * 256 + tid;
      int e = idx >> 4, d8 = (idx & 15) * 8;
      *(u32x4*)(sW + e * 132 + d8) = *(const u32x4*)(WTn + e * 128 + d8);
    }
  }

  // E2: z += res + bias
  size_t base = ((size_t)b * NN + j0) * DD;
#pragma unroll
  for (int p = 0; p < 4; ++p) {
    int idx = p * 256 + tid;
    int j = idx >> 4, c8 = (idx & 15) * 8;
    size_t off = (size_t)j * DD + c8;
    const float4* r4 = (const float4*)(res + base + off);
    float4 r0 = r4[0], r1 = r4[1];
    const float4* bi4 = (const float4*)(bias + c8);
    float4 b0 = bi4[0], b1 = bi4[1];
    float* zz = &z[j * 132 + c8];
    zz[0] += r0.x + b0.x; zz[1] += r0.y + b0.y;
    zz[2] += r0.z + b0.z; zz[3] += r0.w + b0.w;
    zz[4] += r1.x + b1.x; zz[5] += r1.y + b1.y;
    zz[6] += r1.z + b1.z; zz[7] += r1.w + b1.w;
  }
  __syncthreads();

  // E3: LN stats (4 threads per row, interleaved reads)
  {
    int j = tid >> 2, s = tid & 3;
    float sum = 0.f, sq = 0.f;
#pragma unroll
    for (int k = 0; k < 32; ++k) {
      float v = z[j * 132 + s + 4 * k];
      sum += v; sq += v * v;
    }
    sum += __shfl_xor(sum, 1); sq += __shfl_xor(sq, 1);
    sum += __shfl_xor(sum, 2); sq += __shfl_xor(sq, 2);
    if (s == 0) {
      float mu = sum * (1.f / 128.f);
      float var = sq * (1.f / 128.f) - mu * mu;
      smu[j] = mu;
      srs[j] = rsqrtf(var + 1e-5f);
    }
  }
  __syncthreads();

  // E4: normalize + ReLU -> outf; keep h in z for gemm1
  {
    int e = tid & 127;
    float g = gamma[e], bt = beta[e];
#pragma unroll
    for (int p = 0; p < 32; ++p) {
      int idx = p * 256 + tid;
      int j = idx >> 7;
      float v = (z[j * 132 + e] - smu[j]) * srs[j] * g + bt;
      v = fmaxf(v, 0.f);
      outf[base + idx] = v;
      z[j * 132 + e] = v;   // same thread, same slot: no race
    }
  }
  if (!doW) return;
  __syncthreads();  // sW + relu'd z visible

  // E5: gemm1 -> hwTn[e][irow]
  f32x4 acc2[8];
#pragma unroll
  for (int t = 0; t < 8; ++t)
#pragma unroll
    for (int r = 0; r < 4; ++r) acc2[t][r] = 0.f;
  int irow = j0 + w * 16 + m;
  const float* hrow = &z[(w * 16 + m) * 132];
#pragma unroll
  for (int kk = 0; kk < 4; ++kk) {
    int d0 = kk * 32 + q * 8;
    float4 h0 = *(const float4*)(hrow + d0);
    float4 h1 = *(const float4*)(hrow + d0 + 4);
    union { bf16x8 v; unsigned short s[8]; } ub;
    ub.s[0] = f2b(h0.x); ub.s[1] = f2b(h0.y); ub.s[2] = f2b(h0.z); ub.s[3] = f2b(h0.w);
    ub.s[4] = f2b(h1.x); ub.s[5] = f2b(h1.y); ub.s[6] = f2b(h1.z); ub.s[7] = f2b(h1.w);
#pragma unroll
    for (int mt = 0; mt < 8; ++mt) {
      bf16x8 af = *(const bf16x8*)(sW + (mt * 16 + m) * 132 + d0);
      acc2[mt] = __builtin_amdgcn_mfma_f32_16x16x32_bf16(af, ub.v, acc2[mt], 0, 0, 0);
    }
  }
  unsigned short* dst = hwTn + (size_t)b * DD * NN;
#pragma unroll
  for (int mt = 0; mt < 8; ++mt)
#pragma unroll
    for (int r = 0; r < 4; ++r)
      dst[(size_t)(mt * 16 + q * 4 + r) * NN + irow] = f2b(acc2[mt][r]);
}

extern "C" void kernel_launch(void* const* d_in, const int* in_sizes, int n_in,
                              void* d_out, int out_size, void* d_ws, size_t ws_size,
                              hipStream_t stream) {
  const float* X   = (const float*)d_in[0];
  const float* adj = (const float*)d_in[1];
  const float* Ws  = (const float*)d_in[2];
  const float* bs  = (const float*)d_in[3];
  const float* gms = (const float*)d_in[4];
  const float* bts = (const float*)d_in[5];
  float* out = (float*)d_out;

  // ws: adjT bf16 (134MB) | hwT ping-pong bf16 (2 x 8.4MB) | WT bf16 (96KB)
  unsigned short* adjT = (unsigned short*)d_ws;
  unsigned short* hwT0 = adjT + (size_t)BB * NN * NN;
  unsigned short* hwT1 = hwT0 + (size_t)BB * DD * NN;
  unsigned short* WT   = hwT1 + (size_t)BB * DD * NN;

  k_wt<<<dim3(2, 2, 3), 256, 0, stream>>>(Ws, WT);
  k_pre<<<dim3(1056, BB), 256, 0, stream>>>(adj, adjT, X, WT, hwT0);
  for (int l = 0; l < 3; ++l) {
    const float* res = (l == 0) ? X : (const float*)out;
    const unsigned short* WTn = WT + (size_t)((l < 2) ? (l + 1) : 0) * DD * DD;
    unsigned short* hin  = (l & 1) ? hwT1 : hwT0;
    unsigned short* hout = (l & 1) ? hwT0 : hwT1;
    k_layer<<<dim3(NN / 64, BB), 256, 0, stream>>>(adjT, hin, res, bs + l * DD,
                                                   gms + l * DD, bts + l * DD,
                                                   WTn, out, hout, (l < 2) ? 1 : 0);
  }
}

// Round 2
// 539.885 us; speedup vs baseline: 1.0290x; 1.0013x over previous
//
#include <hip/hip_runtime.h>

#define BB 16
#define NN 2048
#define DD 128

typedef __attribute__((ext_vector_type(8))) __bf16 bf16x8;
typedef __attribute__((ext_vector_type(4))) float f32x4;
typedef __attribute__((ext_vector_type(4))) unsigned int u32x4;
typedef __attribute__((address_space(3))) unsigned int lds_u32;
typedef __attribute__((address_space(1))) const unsigned int glob_u32;

static __device__ __forceinline__ unsigned short f2b(float f) {
  union { float f; unsigned int u; } c; c.f = f;
  unsigned int u = c.u;
  unsigned int r = (u + 0x7FFFu + ((u >> 16) & 1u)) >> 16;
  return (unsigned short)r;
}
static __device__ __forceinline__ float b2f(unsigned short u) {
  union { unsigned int u; float f; } c; c.u = ((unsigned int)u) << 16;
  return c.f;
}

// WT[l][e][d] = bf16(W[l][d][e])  -- 96 KB total, L2-resident afterwards
__global__ void k_wt(const float* __restrict__ W, unsigned short* __restrict__ WT) {
  __shared__ float t[64][65];
  int l = blockIdx.z, d0 = blockIdx.x * 64, e0 = blockIdx.y * 64;
  int tid = threadIdx.x;
  const float* src = W + (size_t)l * DD * DD;
  for (int p = 0; p < 16; ++p) {
    int idx = p * 256 + tid;
    int d = idx >> 6, e = idx & 63;
    t[e][d] = src[(size_t)(d0 + d) * DD + (e0 + e)];
  }
  __syncthreads();
  unsigned short* dst = WT + (size_t)l * DD * DD;
  for (int p = 0; p < 4; ++p) {
    int idx = p * 256 + tid;
    int e = idx >> 4, d4 = (idx & 15) * 4;
    ushort4 r;
    r.x = f2b(t[e][d4 + 0]); r.y = f2b(t[e][d4 + 1]);
    r.z = f2b(t[e][d4 + 2]); r.w = f2b(t[e][d4 + 3]);
    *(ushort4*)(dst + (size_t)(e0 + e) * DD + (d0 + d4)) = r;
  }
}

// Merged: x<1024 -> adj transpose tile (float4 reads); x>=1024 -> layer-0 gemm1
__global__ __launch_bounds__(256) void k_pre(const float* __restrict__ adj,
                                             unsigned short* __restrict__ adjT,
                                             const float* __restrict__ X,
                                             const unsigned short* __restrict__ WT,
                                             unsigned short* __restrict__ hwT) {
  int b = blockIdx.y, x = blockIdx.x, tid = threadIdx.x;
  if (x < 1024) {
    __shared__ float t[64][65];
    int j0 = (x >> 5) * 64, i0 = (x & 31) * 64;
    const float* src = adj + (size_t)b * NN * NN;
    // float4 reads (1 KB/wave/instr); scalar transposed LDS writes, 2-way bank (free)
#pragma unroll
    for (int p = 0; p < 4; ++p) {
      int idx = p * 256 + tid;
      int i = idx >> 4, c4 = (idx & 15) * 4;
      float4 v = *(const float4*)(src + (size_t)(i0 + i) * NN + (j0 + c4));
      t[c4 + 0][i] = v.x; t[c4 + 1][i] = v.y;
      t[c4 + 2][i] = v.z; t[c4 + 3][i] = v.w;
    }
    __syncthreads();
    unsigned short* dst = adjT + (size_t)b * NN * NN;
#pragma unroll
    for (int p = 0; p < 4; ++p) {
      int idx = p * 256 + tid;
      int j = idx >> 4, i4 = (idx & 15) * 4;
      ushort4 r;
      r.x = f2b(t[j][i4 + 0]); r.y = f2b(t[j][i4 + 1]);
      r.z = f2b(t[j][i4 + 2]); r.w = f2b(t[j][i4 + 3]);
      *(ushort4*)(dst + (size_t)(j0 + j) * NN + (i0 + i4)) = r;
    }
  } else {
    int i0 = (x - 1024) * 64;
    int lane = tid & 63, w = tid >> 6;
    int q = lane >> 4, m = lane & 15;
    f32x4 acc[8];
#pragma unroll
    for (int t = 0; t < 8; ++t)
#pragma unroll
      for (int r = 0; r < 4; ++r) acc[t][r] = 0.f;
    int irow = i0 + w * 16 + m;
    const float* hrow = X + ((size_t)b * NN + irow) * DD;
#pragma unroll
    for (int kk = 0; kk < 4; ++kk) {
      int d0 = kk * 32 + q * 8;
      float4 h0 = *(const float4*)(hrow + d0);
      float4 h1 = *(const float4*)(hrow + d0 + 4);
      union { bf16x8 v; unsigned short s[8]; } ub;
      ub.s[0] = f2b(h0.x); ub.s[1] = f2b(h0.y); ub.s[2] = f2b(h0.z); ub.s[3] = f2b(h0.w);
      ub.s[4] = f2b(h1.x); ub.s[5] = f2b(h1.y); ub.s[6] = f2b(h1.z); ub.s[7] = f2b(h1.w);
#pragma unroll
      for (int mt = 0; mt < 8; ++mt) {
        bf16x8 af = *(const bf16x8*)(WT + (mt * 16 + m) * 128 + d0);
        acc[mt] = __builtin_amdgcn_mfma_f32_16x16x32_bf16(af, ub.v, acc[mt], 0, 0, 0);
      }
    }
    unsigned short* dst = hwT + (size_t)b * DD * NN;
#pragma unroll
    for (int mt = 0; mt < 8; ++mt)
#pragma unroll
      for (int r = 0; r < 4; ++r)
        dst[(size_t)(mt * 16 + q * 4 + r) * NN + irow] = f2b(acc[mt][r]);
  }
}

// Fused per-layer kernel, 2-phase pipelined (T3-lite):
//   per iter: STAGE(tile t+1 -> buf^1) BEFORE compute(tile t, buf) -> one __syncthreads.
//   The barrier's vmcnt(0) drain lands after ~350 cyc of ds_read+MFMA cover instead of
//   immediately after load issue (old version exposed full latency 32x).
// LDS: 48 KB staging dbuf (z f32 aliases it in the epilogue) + stats. 2 blocks/CU.
// sW dropped: E5 reads WTn fragments direct from global (32 KB, L2-hot; same as k_pre).
__global__ __launch_bounds__(256) void k_layer(const unsigned short* __restrict__ adjT,
                                               const unsigned short* __restrict__ hwT,
                                               const float* __restrict__ res,
                                               const float* __restrict__ bias,
                                               const float* __restrict__ gamma,
                                               const float* __restrict__ beta,
                                               const unsigned short* __restrict__ WTn,
                                               float* __restrict__ outf,
                                               unsigned short* __restrict__ hwTn,
                                               int doW) {
  __shared__ __align__(16) unsigned short sbuf[2 * 12288];  // 2 x (sA 4096 + sH 8192)
  __shared__ float smu[64], srs[64];
  float* z = (float*)sbuf;  // 64x132 f32 = 33.8 KB, alias: staging dead after K-loop

  int tid = threadIdx.x;
  int lane = tid & 63, w = tid >> 6;
  int q = lane >> 4, m = lane & 15;
  int wj = w & 1, we = w >> 1;
  int b = blockIdx.y, j0 = blockIdx.x * 64;
  const unsigned short* At = adjT + (size_t)b * NN * NN;
  const unsigned short* Ht = hwT + (size_t)b * DD * NN;

  // Pre-swizzled global source, linear LDS dest (both-sides-or-neither rule).
  const unsigned short* aSrc[2];
  const unsigned short* hSrc[4];
#pragma unroll
  for (int it = 0; it < 2; ++it) {
    int p = (it * 4 + w) * 64 + lane;
    int r = p >> 3, cg = (p & 7) ^ (r & 7);
    aSrc[it] = At + (size_t)(j0 + r) * NN + cg * 8;
  }
#pragma unroll
  for (int it = 0; it < 4; ++it) {
    int p = (it * 4 + w) * 64 + lane;
    int r = p >> 3, cg = (p & 7) ^ (r & 7);
    hSrc[it] = Ht + (size_t)r * NN + cg * 8;
  }

  f32x4 acc[2][4];
#pragma unroll
  for (int i = 0; i < 2; ++i)
#pragma unroll
    for (int j = 0; j < 4; ++j)
#pragma unroll
      for (int r = 0; r < 4; ++r) acc[i][j][r] = 0.f;

  // Prologue: stage tile 0 into buf0
#pragma unroll
  for (int it = 0; it < 2; ++it) {
    __builtin_amdgcn_global_load_lds((glob_u32*)aSrc[it],
                                     (lds_u32*)(sbuf + (it * 4 + w) * 512), 16, 0, 0);
    aSrc[it] += 64;
  }
#pragma unroll
  for (int it = 0; it < 4; ++it) {
    __builtin_amdgcn_global_load_lds((glob_u32*)hSrc[it],
                                     (lds_u32*)(sbuf + 4096 + (it * 4 + w) * 512), 16, 0, 0);
    hSrc[it] += 64;
  }
  __syncthreads();

  for (int t = 0; t < 32; ++t) {
    const unsigned short* sA = sbuf + (t & 1) * 12288;
    const unsigned short* sH = sA + 4096;
    if (t < 31) {  // issue next-tile loads first: they fly under ds_read+MFMA
      unsigned short* nA = sbuf + ((t + 1) & 1) * 12288;
      unsigned short* nH = nA + 4096;
#pragma unroll
      for (int it = 0; it < 2; ++it) {
        __builtin_amdgcn_global_load_lds((glob_u32*)aSrc[it],
                                         (lds_u32*)(nA + (it * 4 + w) * 512), 16, 0, 0);
        aSrc[it] += 64;
      }
#pragma unroll
      for (int it = 0; it < 4; ++it) {
        __builtin_amdgcn_global_load_lds((glob_u32*)hSrc[it],
                                         (lds_u32*)(nH + (it * 4 + w) * 512), 16, 0, 0);
        hSrc[it] += 64;
      }
    }
#pragma unroll
    for (int kk = 0; kk < 2; ++kk) {
      bf16x8 af[2], bfr[4];
#pragma unroll
      for (int mt = 0; mt < 2; ++mt) {
        int r = wj * 32 + mt * 16 + m;
        int c = (kk * 4 + q) ^ (r & 7);
        af[mt] = *(const bf16x8*)(sA + r * 64 + c * 8);
      }
#pragma unroll
      for (int nt = 0; nt < 4; ++nt) {
        int r = we * 64 + nt * 16 + m;
        int c = (kk * 4 + q) ^ (r & 7);
        bfr[nt] = *(const bf16x8*)(sH + r * 64 + c * 8);
      }
#pragma unroll
      for (int mt = 0; mt < 2; ++mt)
#pragma unroll
        for (int nt = 0; nt < 4; ++nt)
          acc[mt][nt] = __builtin_amdgcn_mfma_f32_16x16x32_bf16(af[mt], bfr[nt], acc[mt][nt], 0, 0, 0);
    }
    __syncthreads();  // vmcnt(0): next tile resident; lgkm done; buf reuse safe
  }
  // Final loop barrier also guarantees all waves' ds_reads done -> z may alias staging.

  // E1: spill accumulators (full-K fp32 sums) into z
#pragma unroll
  for (int mt = 0; mt < 2; ++mt)
#pragma unroll
    for (int nt = 0; nt < 4; ++nt)
#pragma unroll
      for (int r = 0; r < 4; ++r) {
        int row = wj * 32 + mt * 16 + q * 4 + r;
        int col = we * 64 + nt * 16 + m;
        z[row * 132 + col] = acc[mt][nt][r];
      }
  __syncthreads();

  // E2: z += res + bias
  size_t base = ((size_t)b * NN + j0) * DD;
#pragma unroll
  for (int p = 0; p < 4; ++p) {
    int idx = p * 256 + tid;
    int j = idx >> 4, c8 = (idx & 15) * 8;
    size_t off = (size_t)j * DD + c8;
    const float4* r4 = (const float4*)(res + base + off);
    float4 r0 = r4[0], r1 = r4[1];
    const float4* bi4 = (const float4*)(bias + c8);
    float4 b0 = bi4[0], b1 = bi4[1];
    float* zz = &z[j * 132 + c8];
    zz[0] += r0.x + b0.x; zz[1] += r0.y + b0.y;
    zz[2] += r0.z + b0.z; zz[3] += r0.w + b0.w;
    zz[4] += r1.x + b1.x; zz[5] += r1.y + b1.y;
    zz[6] += r1.z + b1.z; zz[7] += r1.w + b1.w;
  }
  __syncthreads();

  // E3: LN stats (4 threads per row, interleaved reads; 2-way bank = free)
  {
    int j = tid >> 2, s = tid & 3;
    float sum = 0.f, sq = 0.f;
#pragma unroll
    for (int k = 0; k < 32; ++k) {
      float v = z[j * 132 + s + 4 * k];
      sum += v; sq += v * v;
    }
    sum += __shfl_xor(sum, 1); sq += __shfl_xor(sq, 1);
    sum += __shfl_xor(sum, 2); sq += __shfl_xor(sq, 2);
    if (s == 0) {
      float mu = sum * (1.f / 128.f);
      float var = sq * (1.f / 128.f) - mu * mu;
      smu[j] = mu;
      srs[j] = rsqrtf(var + 1e-5f);
    }
  }
  __syncthreads();

  // E4: normalize + ReLU -> outf; keep h in z for gemm1
  {
    int e = tid & 127;
    float g = gamma[e], bt = beta[e];
#pragma unroll
    for (int p = 0; p < 32; ++p) {
      int idx = p * 256 + tid;
      int j = idx >> 7;
      float v = (z[j * 132 + e] - smu[j]) * srs[j] * g + bt;
      v = fmaxf(v, 0.f);
      outf[base + idx] = v;
      z[j * 132 + e] = v;   // same thread, same slot: no race
    }
  }
  if (!doW) return;
  __syncthreads();

  // E5: gemm1 -> hwTn[e][irow]; WTn fragments direct from global (L2-hot, 32 KB)
  f32x4 acc2[8];
#pragma unroll
  for (int t = 0; t < 8; ++t)
#pragma unroll
    for (int r = 0; r < 4; ++r) acc2[t][r] = 0.f;
  int irow = j0 + w * 16 + m;
  const float* hrow = &z[(w * 16 + m) * 132];
#pragma unroll
  for (int kk = 0; kk < 4; ++kk) {
    int d0 = kk * 32 + q * 8;
    float4 h0 = *(const float4*)(hrow + d0);
    float4 h1 = *(const float4*)(hrow + d0 + 4);
    union { bf16x8 v; unsigned short s[8]; } ub;
    ub.s[0] = f2b(h0.x); ub.s[1] = f2b(h0.y); ub.s[2] = f2b(h0.z); ub.s[3] = f2b(h0.w);
    ub.s[4] = f2b(h1.x); ub.s[5] = f2b(h1.y); ub.s[6] = f2b(h1.z); ub.s[7] = f2b(h1.w);
#pragma unroll
    for (int mt = 0; mt < 8; ++mt) {
      bf16x8 af = *(const bf16x8*)(WTn + (mt * 16 + m) * 128 + d0);
      acc2[mt] = __builtin_amdgcn_mfma_f32_16x16x32_bf16(af, ub.v, acc2[mt], 0, 0, 0);
    }
  }
  unsigned short* dst = hwTn + (size_t)b * DD * NN;
#pragma unroll
  for (int mt = 0; mt < 8; ++mt)
#pragma unroll
    for (int r = 0; r < 4; ++r)
      dst[(size_t)(mt * 16 + q * 4 + r) * NN + irow] = f2b(acc2[mt][r]);
}

extern "C" void kernel_launch(void* const* d_in, const int* in_sizes, int n_in,
                              void* d_out, int out_size, void* d_ws, size_t ws_size,
                              hipStream_t stream) {
  const float* X   = (const float*)d_in[0];
  const float* adj = (const float*)d_in[1];
  const float* Ws  = (const float*)d_in[2];
  const float* bs  = (const float*)d_in[3];
  const float* gms = (const float*)d_in[4];
  const float* bts = (const float*)d_in[5];
  float* out = (float*)d_out;

  // ws: adjT bf16 (134MB) | hwT ping-pong bf16 (2 x 8.4MB) | WT bf16 (96KB)
  unsigned short* adjT = (unsigned short*)d_ws;
  unsigned short* hwT0 = adjT + (size_t)BB * NN * NN;
  unsigned short* hwT1 = hwT0 + (size_t)BB * DD * NN;
  unsigned short* WT   = hwT1 + (size_t)BB * DD * NN;

  k_wt<<<dim3(2, 2, 3), 256, 0, stream>>>(Ws, WT);
  k_pre<<<dim3(1056, BB), 256, 0, stream>>>(adj, adjT, X, WT, hwT0);
  for (int l = 0; l < 3; ++l) {
    const float* res = (l == 0) ? X : (const float*)out;
    const unsigned short* WTn = WT + (size_t)((l < 2) ? (l + 1) : 0) * DD * DD;
    unsigned short* hin  = (l & 1) ? hwT1 : hwT0;
    unsigned short* hout = (l & 1) ? hwT0 : hwT1;
    k_layer<<<dim3(NN / 64, BB), 256, 0, stream>>>(adjT, hin, res, bs + l * DD,
                                                   gms + l * DD, bts + l * DD,
                                                   WTn, out, hout, (l < 2) ? 1 : 0);
  }
}